// Round 1
// baseline (66746.808 us; speedup 1.0000x reference)
//
#include <hip/hip_runtime.h>
#include <math.h>

#define T 16384

__device__ __forceinline__ float softplusf_(float x) {
    return (x > 15.f) ? x : __logf(1.f + __expf(x));
}
__device__ __forceinline__ float sigmoidf_(float x) {
    return 1.f / (1.f + __expf(-x));
}
__device__ __forceinline__ float tanh_fast(float x) {
    float xc = fminf(fmaxf(x, -15.f), 15.f);
    float e = __expf(2.f * xc);
    return (e - 1.f) / (e + 1.f);
}

// ---------------------------------------------------------------------------
// Precompute x-dependent matvec parts for all timesteps (fully parallel):
//   Aq[t,j] = x[t,:] @ W_q_y[0:128, j]
//   Ae[t,j] = x[t,:] @ W_enc[0:128, j]
//   Ah[t,o] = x[t,:] @ W_ih[65:193, o]
// ---------------------------------------------------------------------------
__global__ __launch_bounds__(256) void k_pre(
    const float* __restrict__ x,
    const float* __restrict__ Wqy, const float* __restrict__ Wenc,
    const float* __restrict__ Wih,
    float* __restrict__ Aq, float* __restrict__ Ae, float* __restrict__ Ah)
{
    __shared__ float xs[16 * 128];
    const int t0 = blockIdx.x * 16;
    for (int r = threadIdx.x; r < 16 * 128; r += 256) xs[r] = x[t0 * 128 + r];
    __syncthreads();
    const int j = threadIdx.x;
    for (int tt = 0; tt < 16; ++tt) {
        float aq = 0.f, ae = 0.f;
#pragma unroll 8
        for (int i = 0; i < 128; ++i) {
            float xv = xs[tt * 128 + i];
            aq = fmaf(xv, Wqy[i * 256 + j], aq);
            ae = fmaf(xv, Wenc[i * 256 + j], ae);
        }
        Aq[(size_t)(t0 + tt) * 256 + j] = aq;
        Ae[(size_t)(t0 + tt) * 256 + j] = ae;
    }
    if (j < 128) {
        for (int tt = 0; tt < 16; ++tt) {
            float ah = 0.f;
#pragma unroll 8
            for (int i = 0; i < 128; ++i)
                ah = fmaf(xs[tt * 128 + i], Wih[(65 + i) * 128 + j], ah);
            Ah[(size_t)(t0 + tt) * 128 + j] = ah;
        }
    }
}

// ---------------------------------------------------------------------------
// Sequential scan: 1 block, 512 threads, recurrent weights in registers.
// Produces trajectory: h_st[T,128], z_st[T,64], em_st/es_st[T,64], y_st[T].
// ---------------------------------------------------------------------------
__global__ __launch_bounds__(512, 1) void k_scan(
    const float* __restrict__ Wqy, const float* __restrict__ qpr,
    const float* __restrict__ Wenc,
    const float* __restrict__ Wem0, const float* __restrict__ Wes0,
    const float* __restrict__ Wih, const float* __restrict__ Whh,
    const float* __restrict__ yin_g, const float* __restrict__ eu_g,
    const float* __restrict__ ez_g,
    const float* __restrict__ Aq, const float* __restrict__ Ae,
    const float* __restrict__ Ah,
    float* __restrict__ h_st, float* __restrict__ z_st,
    float* __restrict__ em_st, float* __restrict__ es_st,
    float* __restrict__ y_st)
{
    const int tid = threadIdx.x;
    // S1/S3 mapping: 256 outputs x 2 chunks of 64 over h
    const int j  = tid >> 1, c1 = tid & 1;
    // S4 mapping: 64 m x {mean,std} x 4 chunks of 64 over eh
    const int m4 = tid >> 3; const int k4 = (tid >> 2) & 1; const int c4 = tid & 3;
    // S5 mapping: 128 outputs x 4 chunks (16 z + 32 h each)
    const int o5 = tid >> 2, c5 = tid & 3;

    // --- load persistent weights into registers (static indexing) ---
    float wqh[64], weh[64], wms[64], wz5[16], wh5[32];
#pragma unroll
    for (int k = 0; k < 64; ++k) wqh[k] = Wqy[(128 + c1 * 64 + k) * 256 + j];
#pragma unroll
    for (int k = 0; k < 64; ++k) weh[k] = Wenc[(129 + c1 * 64 + k) * 256 + j];
    const float wey = Wenc[128 * 256 + j];
    const float qpj = qpr[j];
    const float* Wm = k4 ? Wes0 : Wem0;
#pragma unroll
    for (int k = 0; k < 64; ++k) wms[k] = Wm[(c4 * 64 + k) * 64 + m4];
#pragma unroll
    for (int k = 0; k < 16; ++k) wz5[k] = Wih[(1 + c5 * 16 + k) * 128 + o5];
#pragma unroll
    for (int k = 0; k < 32; ++k) wh5[k] = Whh[(c5 * 32 + k) * 128 + o5];
    const float wihy = Wih[o5];

    __shared__ float h_lds[2][128];
    __shared__ float eh_lds[256];
    __shared__ float z_lds[64];
    __shared__ float red[8];
    if (tid < 128) { h_lds[0][tid] = 0.f; h_lds[1][tid] = 0.f; }
    __syncthreads();

    // prefetch t=0 stream values
    float aq_n = Aq[j];
    float ae_n = Ae[j];
    float yin_n = yin_g[0];
    float eu_n = eu_g[0];

    for (int t = 0; t < T; ++t) {
        const int cur = t & 1;
        const float aq = aq_n, ae = ae_n, yin = yin_n, eu = eu_n;
        const int tn = (t + 1 < T) ? t + 1 : t;
        aq_n = Aq[(size_t)tn * 256 + j];
        ae_n = Ae[(size_t)tn * 256 + j];
        yin_n = yin_g[tn];
        eu_n = eu_g[tn];
        const float ez = ez_g[(size_t)t * 64 + m4];
        const float ah = Ah[(size_t)t * 128 + o5];
        const float* __restrict__ hb = &h_lds[cur][c1 * 64];

        float y_t;
        if (yin == -1.0f) {   // unlabeled: need q-chain (uniform branch)
            float a0 = 0.f, a1 = 0.f, a2 = 0.f, a3 = 0.f;
#pragma unroll
            for (int k = 0; k < 64; k += 4) {
                a0 = fmaf(hb[k],     wqh[k],     a0);
                a1 = fmaf(hb[k + 1], wqh[k + 1], a1);
                a2 = fmaf(hb[k + 2], wqh[k + 2], a2);
                a3 = fmaf(hb[k + 3], wqh[k + 3], a3);
            }
            float s = (a0 + a1) + (a2 + a3);
            s += __shfl_xor(s, 1);
            float qh = fmaxf(aq + s, 0.f);
            float cq = (c1 == 0) ? qh * qpj : 0.f;
#pragma unroll
            for (int d = 1; d < 64; d <<= 1) cq += __shfl_xor(cq, d);
            if ((tid & 63) == 0) red[tid >> 6] = cq;
            __syncthreads();                               // B1
            float qlog = ((red[0] + red[1]) + (red[2] + red[3])) +
                         ((red[4] + red[5]) + (red[6] + red[7]));
            // log(q)-log(1-q) == qlog for q = sigmoid(qlog)
            y_t = sigmoidf_((__logf(eu) - __logf(1.f - eu)) + qlog);
        } else {
            y_t = yin;   // labeled
        }

        // S3: eh = relu(Ae + y*wey + h @ We_h)
        {
            float a0 = 0.f, a1 = 0.f, a2 = 0.f, a3 = 0.f;
#pragma unroll
            for (int k = 0; k < 64; k += 4) {
                a0 = fmaf(hb[k],     weh[k],     a0);
                a1 = fmaf(hb[k + 1], weh[k + 1], a1);
                a2 = fmaf(hb[k + 2], weh[k + 2], a2);
                a3 = fmaf(hb[k + 3], weh[k + 3], a3);
            }
            float s = (a0 + a1) + (a2 + a3);
            s += __shfl_xor(s, 1);
            float eh = fmaxf(fmaf(y_t, wey, ae) + s, 0.f);
            if (c1 == 0) eh_lds[j] = eh;
        }
        __syncthreads();                                   // B3

        // S4: em/es = eh @ W_enc_mean/std ; z = ez*softplus(es)+em
        {
            const float* __restrict__ eb = &eh_lds[c4 * 64];
            float a0 = 0.f, a1 = 0.f, a2 = 0.f, a3 = 0.f;
#pragma unroll
            for (int k = 0; k < 64; k += 4) {
                a0 = fmaf(eb[k],     wms[k],     a0);
                a1 = fmaf(eb[k + 1], wms[k + 1], a1);
                a2 = fmaf(eb[k + 2], wms[k + 2], a2);
                a3 = fmaf(eb[k + 3], wms[k + 3], a3);
            }
            float s = (a0 + a1) + (a2 + a3);
            s += __shfl_xor(s, 1);
            s += __shfl_xor(s, 2);
            float other = __shfl_xor(s, 4);
            float em_pre = k4 ? other : s;
            float es_pre = k4 ? s : other;
            float es = softplusf_(es_pre);
            float zm = fmaf(ez, es, em_pre);
            if ((tid & 7) == 0) {
                z_lds[m4] = zm;
                z_st[(size_t)t * 64 + m4] = zm;
                em_st[(size_t)t * 64 + m4] = em_pre;
                es_st[(size_t)t * 64 + m4] = es;
            }
        }
        __syncthreads();                                   // B4

        // S5: h_new = tanh(Ah + y*wihy + z @ Wih_z + h @ W_hh)
        {
            const float* __restrict__ zb  = &z_lds[c5 * 16];
            const float* __restrict__ hb5 = &h_lds[cur][c5 * 32];
            float a0 = 0.f, a1 = 0.f, a2 = 0.f, a3 = 0.f;
#pragma unroll
            for (int k = 0; k < 16; k += 4) {
                a0 = fmaf(zb[k],     wz5[k],     a0);
                a1 = fmaf(zb[k + 1], wz5[k + 1], a1);
                a2 = fmaf(zb[k + 2], wz5[k + 2], a2);
                a3 = fmaf(zb[k + 3], wz5[k + 3], a3);
            }
#pragma unroll
            for (int k = 0; k < 32; k += 4) {
                a0 = fmaf(hb5[k],     wh5[k],     a0);
                a1 = fmaf(hb5[k + 1], wh5[k + 1], a1);
                a2 = fmaf(hb5[k + 2], wh5[k + 2], a2);
                a3 = fmaf(hb5[k + 3], wh5[k + 3], a3);
            }
            float s = (a0 + a1) + (a2 + a3);
            s += __shfl_xor(s, 1);
            s += __shfl_xor(s, 2);
            float hn = tanh_fast(fmaf(y_t, wihy, ah) + s);
            if (c5 == 0) {
                h_lds[cur ^ 1][o5] = hn;
                h_st[(size_t)t * 128 + o5] = hn;
            }
            if (tid == 0) y_st[t] = y_t;
        }
        __syncthreads();                                   // B5
    }
}

// ---------------------------------------------------------------------------
// Post-pass: one block per timestep; recompute everything off the critical
// path from the stored trajectory; write 7 per-step loss partials.
// ---------------------------------------------------------------------------
__global__ __launch_bounds__(256) void k_post(
    const float* __restrict__ x, const float* __restrict__ yin_g,
    const float* __restrict__ Wpz, const float* __restrict__ Wpzm,
    const float* __restrict__ Wpzs,
    const float* __restrict__ Wpy, const float* __restrict__ ppr,
    const float* __restrict__ Wqy, const float* __restrict__ qpr,
    const float* __restrict__ Wd, const float* __restrict__ Wdm,
    const float* __restrict__ Wds,
    const float* __restrict__ Aq,
    const float* __restrict__ h_st, const float* __restrict__ z_st,
    const float* __restrict__ em_st, const float* __restrict__ es_st,
    const float* __restrict__ y_st,
    float* __restrict__ part)
{
    const float CC = -0.9189385332046727f;  // -0.5*log(2*pi)
    const int t = blockIdx.x;
    const int tid = threadIdx.x;
    __shared__ float xp[128], xdv[128], xcv[128], hp[128];
    __shared__ float zp[64], ztv[64], emv[64], esv[64];
    __shared__ float pzh[256], dhv[256];
    __shared__ float pmv[64], psv[64], dmv[128], dsv[128];
    __shared__ float rl[16];

    const int tp = t ? (t - 1) : (T - 1);
    if (tid < 128) {
        xp[tid]  = x[(size_t)tp * 128 + tid];
        xdv[tid] = t ? x[(size_t)(t - 1) * 128 + tid] : 0.f;   // decoder carry init = 0
        xcv[tid] = x[(size_t)t * 128 + tid];
        hp[tid]  = t ? h_st[(size_t)(t - 1) * 128 + tid] : 0.f;
    } else {
        int m = tid - 128;
        if (m < 64) {
            zp[m]  = t ? z_st[(size_t)(t - 1) * 64 + m] : 0.f;
            ztv[m] = z_st[(size_t)t * 64 + m];
        } else {
            m -= 64;
            emv[m] = em_st[(size_t)t * 64 + m];
            esv[m] = es_st[(size_t)t * 64 + m];
        }
    }
    __syncthreads();

    const float y_t = y_st[t];
    const float y_prev = t ? y_st[t - 1] : 0.f;
    const float lf = (yin_g[t] != -1.0f) ? 1.f : 0.f;
    const int jj = tid;

    // p(y) logit contribution
    float ap = 0.f;
#pragma unroll 4
    for (int i = 0; i < 128; ++i) ap = fmaf(xp[i], Wpy[i * 256 + jj], ap);
    ap = fmaf(y_prev, Wpy[128 * 256 + jj], ap);
    float cp = fmaxf(ap, 0.f) * ppr[jj];

    // q(y) logit contribution
    float aqv = Aq[(size_t)t * 256 + jj];
#pragma unroll 4
    for (int i = 0; i < 128; ++i) aqv = fmaf(hp[i], Wqy[(128 + i) * 256 + jj], aqv);
    float cq = fmaxf(aqv, 0.f) * qpr[jj];

    // prior z hidden
    float az = 0.f;
#pragma unroll 4
    for (int m = 0; m < 64; ++m) az = fmaf(zp[m], Wpz[m * 256 + jj], az);
    pzh[jj] = fmaxf(az, 0.f);

    // decoder hidden
    float ad = 0.f;
#pragma unroll 4
    for (int i = 0; i < 128; ++i) ad = fmaf(xdv[i], Wd[i * 256 + jj], ad);
#pragma unroll 4
    for (int m = 0; m < 64; ++m) ad = fmaf(ztv[m], Wd[(128 + m) * 256 + jj], ad);
    ad = fmaf(y_t, Wd[192 * 256 + jj], ad);
    dhv[jj] = fmaxf(ad, 0.f);
    __syncthreads();

    // dm/ds: 256 threads (128 dims x {mean,std})
    {
        const int i_ = tid & 127;
        const float* W = (tid < 128) ? Wdm : Wds;
        float a = 0.f;
#pragma unroll 4
        for (int q2 = 0; q2 < 256; ++q2) a = fmaf(dhv[q2], W[q2 * 128 + i_], a);
        if (tid < 128) dmv[i_] = a; else dsv[i_] = softplusf_(a);
    }
    // pm/ps: 128 threads (64 dims x {mean,std})
    if (tid < 128) {
        const int m = tid & 63;
        const float* W = (tid < 64) ? Wpzm : Wpzs;
        float a = 0.f;
#pragma unroll 4
        for (int q2 = 0; q2 < 256; ++q2) a = fmaf(pzh[q2], W[q2 * 64 + m], a);
        if (tid < 64) pmv[m] = a; else psv[m] = softplusf_(a);
    }
    __syncthreads();

    float kldc = 0.f, recc = 0.f;
    if (tid < 64) {
        float es = esv[tid], em = emv[tid], pm = pmv[tid], ps = psv[tid];
        float d = em - pm;
        kldc = __logf(ps / es) + (es * es + d * d) / (2.f * ps * ps) - 0.5f;
    }
    if (tid < 128) {
        float dm = dmv[tid], ds = dsv[tid], xv = xcv[tid];
        float d = xv - dm;
        recc = CC + __logf(ds) + d * d / (2.f * ds * ds);
    }

    // block-reduce 4 values
#pragma unroll
    for (int d = 1; d < 64; d <<= 1) {
        cp += __shfl_xor(cp, d);
        cq += __shfl_xor(cq, d);
        kldc += __shfl_xor(kldc, d);
        recc += __shfl_xor(recc, d);
    }
    if ((tid & 63) == 0) {
        const int w = tid >> 6;
        rl[w * 4 + 0] = cp; rl[w * 4 + 1] = cq;
        rl[w * 4 + 2] = kldc; rl[w * 4 + 3] = recc;
    }
    __syncthreads();
    if (tid == 0) {
        float plog = rl[0] + rl[4] + rl[8]  + rl[12];
        float qlog = rl[1] + rl[5] + rl[9]  + rl[13];
        float kld  = rl[2] + rl[6] + rl[10] + rl[14];
        float rec  = rl[3] + rl[7] + rl[11] + rl[15];
        float p = sigmoidf_(plog), q = sigmoidf_(qlog);
        float bce  = -(y_t * __logf(p) + (1.f - y_t) * __logf(1.f - p));
        float addt = y_t * __logf(p * q) + (1.f - y_t) * __logf((1.f - p) * (1.f - q));
        float kcat = p * __logf(p / q) + (1.f - p) * __logf((1.f - p) / (1.f - q));
        float ul = 1.f - lf;
        float* pr = part + (size_t)t * 7;
        pr[0] = lf * kld;  pr[1] = lf * rec;  pr[2] = lf * bce;
        pr[3] = ul * kld;  pr[4] = ul * rec;  pr[5] = ul * kcat;
        pr[6] = lf * addt;
    }
}

// ---------------------------------------------------------------------------
// Deterministic final reduction of the per-step partials (7 outputs).
// ---------------------------------------------------------------------------
__global__ __launch_bounds__(256) void k_final(const float* __restrict__ part,
                                               float* __restrict__ out)
{
    const int o = blockIdx.x;
    float s = 0.f;
    for (int b = threadIdx.x; b < T; b += 256) s += part[(size_t)b * 7 + o];
#pragma unroll
    for (int d = 1; d < 64; d <<= 1) s += __shfl_xor(s, d);
    __shared__ float l[4];
    if ((threadIdx.x & 63) == 0) l[threadIdx.x >> 6] = s;
    __syncthreads();
    if (threadIdx.x == 0) out[o] = (l[0] + l[1]) + (l[2] + l[3]);
}

extern "C" void kernel_launch(void* const* d_in, const int* in_sizes, int n_in,
                              void* d_out, int out_size, void* d_ws, size_t ws_size,
                              hipStream_t stream) {
    (void)in_sizes; (void)n_in; (void)out_size; (void)ws_size;
    const float* x    = (const float*)d_in[0];
    const float* yin  = (const float*)d_in[1];
    const float* ez   = (const float*)d_in[2];
    const float* eu   = (const float*)d_in[3];
    const float* Wpz  = (const float*)d_in[4];
    const float* Wpzm = (const float*)d_in[5];
    const float* Wpzs = (const float*)d_in[6];
    const float* Wpy  = (const float*)d_in[7];
    const float* ppr  = (const float*)d_in[8];
    const float* Wqy  = (const float*)d_in[9];
    const float* qpr  = (const float*)d_in[10];
    const float* Wenc = (const float*)d_in[11];
    const float* Wem  = (const float*)d_in[12];
    const float* Wes  = (const float*)d_in[13];
    const float* Wd   = (const float*)d_in[14];
    const float* Wdm  = (const float*)d_in[15];
    const float* Wds  = (const float*)d_in[16];
    const float* Wih  = (const float*)d_in[17];
    const float* Whh  = (const float*)d_in[18];

    float* ws = (float*)d_ws;
    float* Aq    = ws;                           // T*256
    float* Ae    = Aq    + (size_t)T * 256;      // T*256
    float* Ah    = Ae    + (size_t)T * 256;      // T*128
    float* h_st  = Ah    + (size_t)T * 128;      // T*128
    float* z_st  = h_st  + (size_t)T * 128;      // T*64
    float* em_st = z_st  + (size_t)T * 64;       // T*64
    float* es_st = em_st + (size_t)T * 64;       // T*64
    float* y_st  = es_st + (size_t)T * 64;       // T
    float* part  = y_st  + (size_t)T;            // T*7

    k_pre<<<T / 16, 256, 0, stream>>>(x, Wqy, Wenc, Wih, Aq, Ae, Ah);
    k_scan<<<1, 512, 0, stream>>>(Wqy, qpr, Wenc, Wem, Wes, Wih, Whh,
                                  yin, eu, ez, Aq, Ae, Ah,
                                  h_st, z_st, em_st, es_st, y_st);
    k_post<<<T, 256, 0, stream>>>(x, yin, Wpz, Wpzm, Wpzs, Wpy, ppr, Wqy, qpr,
                                  Wd, Wdm, Wds, Aq, h_st, z_st, em_st, es_st,
                                  y_st, part);
    k_final<<<7, 256, 0, stream>>>(part, (float*)d_out);
}